// Round 9
// baseline (60.642 us; speedup 1.0000x reference)
//
#include <hip/hip_runtime.h>
#include <math.h>

#define NPOINTS 32768
#define NPRIMS  2048
#define BLK     256

typedef float v2f __attribute__((ext_vector_type(2)));

// 64-byte packed record for a pair of primitives (SoA-in-pairs):
//  q0 = (mux0, mux1, muy0, muy1)
//  q1 = (muz0, muz1, amp0, amp1)
//  q2 = (gx0,  gx1,  gy0,  gy1 )   g = -0.5*log2(e)/s^2
//  q3 = (gz0,  gz1,  ph0,  ph1 )   ph in revolutions (phase/2pi)
struct PrimPair { float4 q0, q1, q2, q3; };

// Taylor coefficients for sin(2*pi*v), cos(2*pi*v), v in [-0.5, 0.5].
// Held in VGPRs (asm-pinned) because VOP3P cannot encode literals and the
// compiler otherwise rematerializes them per use (round-7 regression).
struct Poly {
    float s0, s1, s2, s3, s4, s5, s6;
    float c1, c2, c3, c4, c5, c6, c7;
};

// Robust scalar-frequency decode (2400000000 in any plausible encoding).
__device__ __forceinline__ float read_freq(const void* p) {
    const unsigned* w = (const unsigned*)p;
    unsigned lo = w[0];
    float ff = __uint_as_float(lo);
    if (ff >= 1.0e5f && ff <= 1.0e13f) return ff;       // float32
    if (lo != 0u) return (float)lo;                      // int32-wrap / int64 lo
    double d = *(const double*)p;                        // lo==0 -> 8-byte dtype
    if (d >= 1.0e5 && d <= 1.0e13) return (float)d;      // float64
    unsigned long long v = ((unsigned long long)w[1] << 32) | lo;
    return (float)v;                                     // int64 (hi-word path)
}

__global__ __launch_bounds__(BLK) void prep_kernel(
        const float* __restrict__ pos,
        const float* __restrict__ scl,
        const float* __restrict__ amp,
        const float* __restrict__ ph,
        PrimPair* __restrict__ pp) {
    int j = blockIdx.x * blockDim.x + threadIdx.x;
    if (j >= NPRIMS / 2) return;
    const float KE     = -0.72134752044448169f;   // -0.5*log2(e)
    const float INV2PI =  0.15915494309189535f;
    int p0 = 2 * j, p1 = 2 * j + 1;
    float s0x = scl[3*p0+0], s0y = scl[3*p0+1], s0z = scl[3*p0+2];
    float s1x = scl[3*p1+0], s1y = scl[3*p1+1], s1z = scl[3*p1+2];
    PrimPair P;
    P.q0 = make_float4(pos[3*p0+0], pos[3*p1+0], pos[3*p0+1], pos[3*p1+1]);
    P.q1 = make_float4(pos[3*p0+2], pos[3*p1+2], amp[p0], amp[p1]);
    P.q2 = make_float4(KE / (s0x*s0x), KE / (s1x*s1x), KE / (s0y*s0y), KE / (s1y*s1y));
    P.q3 = make_float4(KE / (s0z*s0z), KE / (s1z*s1z), ph[p0] * INV2PI, ph[p1] * INV2PI);
    pp[j] = P;
}

// Packed sincos(2*pi*t): rndne range-reduce to v in [-0.5,0.5], then
// Taylor-13 (sin) / Taylor-14 (cos) in w = v^2. All pk_fma on the main pipe.
__device__ __forceinline__ void pk_sincos_rev(v2f tp, const Poly& K, v2f& s, v2f& c) {
    v2f n  = {__builtin_rintf(tp.x), __builtin_rintf(tp.y)};
    v2f v  = tp - n;
    v2f w  = v * v;
    v2f ps = __builtin_elementwise_fma(w, (v2f){K.s6, K.s6}, (v2f){K.s5, K.s5});
    ps = __builtin_elementwise_fma(w, ps, (v2f){K.s4, K.s4});
    ps = __builtin_elementwise_fma(w, ps, (v2f){K.s3, K.s3});
    ps = __builtin_elementwise_fma(w, ps, (v2f){K.s2, K.s2});
    ps = __builtin_elementwise_fma(w, ps, (v2f){K.s1, K.s1});
    ps = __builtin_elementwise_fma(w, ps, (v2f){K.s0, K.s0});
    s  = v * ps;
    v2f pc = __builtin_elementwise_fma(w, (v2f){K.c7, K.c7}, (v2f){K.c6, K.c6});
    pc = __builtin_elementwise_fma(w, pc, (v2f){K.c5, K.c5});
    pc = __builtin_elementwise_fma(w, pc, (v2f){K.c4, K.c4});
    pc = __builtin_elementwise_fma(w, pc, (v2f){K.c3, K.c3});
    pc = __builtin_elementwise_fma(w, pc, (v2f){K.c2, K.c2});
    pc = __builtin_elementwise_fma(w, pc, (v2f){K.c1, K.c1});
    c  = __builtin_elementwise_fma(w, pc, (v2f){1.0f, 1.0f});   // 1.0 = inline const
}

// One point vs one primitive-pair. sqrt/exp2 stay on the trans pipe (2 ops);
// sincos runs as pk polynomials on the main VALU pipe.
__device__ __forceinline__ void eval_pair(const PrimPair& P, const Poly& K,
                                          v2f xx, v2f yy, v2f zz, v2f kr2,
                                          v2f& re, v2f& im) {
    v2f mux = {P.q0.x, P.q0.y}, muy = {P.q0.z, P.q0.w};
    v2f muz = {P.q1.x, P.q1.y}, am2 = {P.q1.z, P.q1.w};
    v2f gx  = {P.q2.x, P.q2.y}, gy  = {P.q2.z, P.q2.w};
    v2f gz  = {P.q3.x, P.q3.y}, ph2 = {P.q3.z, P.q3.w};

    v2f dx = xx - mux, dy = yy - muy, dz = zz - muz;
    v2f t0 = dx * dx, t1 = dy * dy, t2 = dz * dz;
    v2f e  = t0 * gx + t1 * gy + t2 * gz;          // <= 0 (pk_fma chain)
    v2f d2 = t0 + t1 + t2;
    d2 = __builtin_elementwise_max(d2, (v2f){1e-12f, 1e-12f});

    v2f r2 = {__builtin_amdgcn_sqrtf(d2.x), __builtin_amdgcn_sqrtf(d2.y)};
    v2f ex = {__builtin_amdgcn_exp2f(e.x),  __builtin_amdgcn_exp2f(e.y)};
    v2f w2 = am2 * ex;
    v2f tp = __builtin_elementwise_fma(kr2, r2, ph2);   // phase in revolutions
    v2f s2, c2;
    pk_sincos_rev(tp, K, s2, c2);
    re = __builtin_elementwise_fma(w2, c2, re);
    im = __builtin_elementwise_fma(w2, s2, im);
}

// Each block: BLK*PPT points x (NPRIMS/NSPLIT) prims. Prim records via
// wave-uniform s_load; PPT points per thread amortize each 64B record.
template <int NSPLIT, int PPT>
__global__ __launch_bounds__(BLK) void field_kernel(
        const float* __restrict__ qp,
        const PrimPair* __restrict__ pp,
        const void* __restrict__ freq_p,
        float2* __restrict__ part) {
    constexpr int PAIRS = (NPRIMS / NSPLIT) / 2;
    const int nb = blockIdx.x * (BLK * PPT) + threadIdx.x;
    const float kr = read_freq(freq_p) / 299792458.0f;   // cycles per metre
    const v2f kr2 = {kr, kr};

    // Poly constants, pinned live in VGPRs (opaque asm defeats remat).
    Poly K;
    K.s0 =   6.283185307179586f;  K.s1 = -41.34170224039976f;
    K.s2 =  81.60524927607504f;   K.s3 = -76.70585975306136f;
    K.s4 =  42.05869394489765f;   K.s5 = -15.094642576822123f;
    K.s6 =   3.8199525848482824f;
    K.c1 = -19.739208802178716f;  K.c2 =  64.93939402266829f;
    K.c3 = -85.45681720669372f;   K.c4 =  60.24464137187665f;
    K.c5 = -26.426256783358706f;  K.c6 =   7.903536371318467f;
    K.c7 =  -1.714370232222585f;
    asm volatile("" : "+v"(K.s0), "+v"(K.s1), "+v"(K.s2), "+v"(K.s3),
                      "+v"(K.s4), "+v"(K.s5), "+v"(K.s6),
                      "+v"(K.c1), "+v"(K.c2), "+v"(K.c3), "+v"(K.c4),
                      "+v"(K.c5), "+v"(K.c6), "+v"(K.c7));

    v2f xx[PPT], yy[PPT], zz[PPT], re[PPT], im[PPT];
    #pragma unroll
    for (int i = 0; i < PPT; ++i) {
        int n = nb + i * BLK;
        xx[i] = (v2f){qp[3*n+0], qp[3*n+0]};
        yy[i] = (v2f){qp[3*n+1], qp[3*n+1]};
        zz[i] = (v2f){qp[3*n+2], qp[3*n+2]};
        re[i] = (v2f){0.0f, 0.0f};
        im[i] = (v2f){0.0f, 0.0f};
    }

    const int base = blockIdx.y * PAIRS;
    #pragma unroll 2
    for (int j = 0; j < PAIRS; ++j) {
        PrimPair P = pp[base + j];                 // wave-uniform -> s_load
        #pragma unroll
        for (int i = 0; i < PPT; ++i)
            eval_pair(P, K, xx[i], yy[i], zz[i], kr2, re[i], im[i]);
    }

    #pragma unroll
    for (int i = 0; i < PPT; ++i) {
        int n = nb + i * BLK;
        part[(size_t)blockIdx.y * NPOINTS + n] =
            make_float2(re[i].x + re[i].y, im[i].x + im[i].y);
    }
}

template <int NSPLIT>
__global__ __launch_bounds__(BLK) void reduce_kernel(const float2* __restrict__ part,
                                                     float* __restrict__ out) {
    int n = blockIdx.x * blockDim.x + threadIdx.x;
    float re = 0.0f, im = 0.0f;
    #pragma unroll
    for (int s = 0; s < NSPLIT; ++s) {
        float2 v = part[(size_t)s * NPOINTS + n];
        re += v.x; im += v.y;
    }
    out[n]           = re;   // planar: real block then imag block
    out[NPOINTS + n] = im;
}

// Fallback (tiny workspace): LDS kernel, single pass, direct planar output.
__global__ __launch_bounds__(BLK) void field_fallback(
        const float* __restrict__ qp,
        const float* __restrict__ pos,
        const float* __restrict__ scl,
        const float* __restrict__ amp,
        const float* __restrict__ ph,
        const void*  __restrict__ freq_p,
        float*       __restrict__ out) {
    __shared__ float4 sA[128];
    __shared__ float4 sB[128];
    const int n = blockIdx.x * BLK + threadIdx.x;
    const float x = qp[3*n+0], y = qp[3*n+1], z = qp[3*n+2];
    const float kr = read_freq(freq_p) / 299792458.0f;
    const float KE = -0.72134752044448169f, INV2PI = 0.15915494309189535f;
    float re = 0.0f, im = 0.0f;
    for (int tile = 0; tile < NPRIMS / 128; ++tile) {
        __syncthreads();
        if (threadIdx.x < 128) {
            int p = tile * 128 + threadIdx.x;
            float sx = scl[3*p+0], sy = scl[3*p+1], sz = scl[3*p+2];
            sA[threadIdx.x] = make_float4(pos[3*p+0], pos[3*p+1], pos[3*p+2], amp[p]);
            sB[threadIdx.x] = make_float4(KE/(sx*sx), KE/(sy*sy), KE/(sz*sz), ph[p]*INV2PI);
        }
        __syncthreads();
        #pragma unroll 8
        for (int p = 0; p < 128; ++p) {
            float4 a = sA[p];
            float4 b = sB[p];
            float dx = x - a.x, dy = y - a.y, dz = z - a.z;
            float t0 = dx*dx, t1 = dy*dy, t2 = dz*dz;
            float e  = fmaf(t0, b.x, fmaf(t1, b.y, t2 * b.z));
            float d2 = t0 + t1 + t2;
            float r  = __builtin_amdgcn_sqrtf(fmaxf(d2, 1e-12f));
            float w  = a.w * __builtin_amdgcn_exp2f(e);
            float tp = __builtin_amdgcn_fractf(fmaf(kr, r, b.w));
            float s  = __builtin_amdgcn_sinf(tp);
            float c  = __builtin_amdgcn_cosf(tp);
            re = fmaf(w, c, re);
            im = fmaf(w, s, im);
        }
    }
    out[n]           = re;
    out[NPOINTS + n] = im;
}

extern "C" void kernel_launch(void* const* d_in, const int* in_sizes, int n_in,
                              void* d_out, int out_size, void* d_ws, size_t ws_size,
                              hipStream_t stream) {
    const float* qp  = (const float*)d_in[0];
    const float* pos = (const float*)d_in[1];
    const float* scl = (const float*)d_in[2];
    const float* amp = (const float*)d_in[3];
    const float* ph  = (const float*)d_in[4];
    const void*  fq  = d_in[5];
    float* out = (float*)d_out;

    const size_t packed_bytes = (size_t)(NPRIMS / 2) * sizeof(PrimPair);      // 64 KB
    const size_t ps32 = packed_bytes + (size_t)32 * NPOINTS * sizeof(float2); // +8 MB
    const size_t ps16 = packed_bytes + (size_t)16 * NPOINTS * sizeof(float2); // +4 MB

    if (ws_size >= ps32) {
        // 2048 blocks, 2 points/thread, 32 prim-pairs per block
        PrimPair* pp   = (PrimPair*)d_ws;
        float2*   part = (float2*)((char*)d_ws + packed_bytes);
        prep_kernel<<<dim3((NPRIMS/2 + BLK - 1) / BLK), dim3(BLK), 0, stream>>>(pos, scl, amp, ph, pp);
        field_kernel<32, 2><<<dim3(NPOINTS / (BLK * 2), 32), dim3(BLK), 0, stream>>>(qp, pp, fq, part);
        reduce_kernel<32><<<dim3(NPOINTS / BLK), dim3(BLK), 0, stream>>>(part, out);
    } else if (ws_size >= ps16) {
        PrimPair* pp   = (PrimPair*)d_ws;
        float2*   part = (float2*)((char*)d_ws + packed_bytes);
        prep_kernel<<<dim3((NPRIMS/2 + BLK - 1) / BLK), dim3(BLK), 0, stream>>>(pos, scl, amp, ph, pp);
        field_kernel<16, 1><<<dim3(NPOINTS / BLK, 16), dim3(BLK), 0, stream>>>(qp, pp, fq, part);
        reduce_kernel<16><<<dim3(NPOINTS / BLK), dim3(BLK), 0, stream>>>(part, out);
    } else {
        field_fallback<<<dim3(NPOINTS / BLK), dim3(BLK), 0, stream>>>(qp, pos, scl, amp, ph, fq, out);
    }
}

// Round 10
// 50.741 us; speedup vs baseline: 1.1951x; 1.1951x over previous
//
#include <hip/hip_runtime.h>
#include <math.h>

#define NPOINTS 32768
#define NPRIMS  2048
#define BLK     256

typedef float v2f __attribute__((ext_vector_type(2)));

// 64-byte record for ONE primitive, every scalar DUPLICATED so that an
// s_load'd SGPR pair (even-aligned) can feed VOP3P packed ops directly as a
// broadcast operand — no v_mov assembly (round-9 post-mortem: ~16 v_mov per
// eval was ~25% of VALU busy).
//  q0 = (mux, mux, muy, muy)
//  q1 = (muz, muz, amp, amp)
//  q2 = (gx,  gx,  gy,  gy )   g = -0.5*log2(e)/s^2
//  q3 = (gz,  gz,  ph,  ph )   ph in revolutions (phase/2pi)
struct PrimDup { float4 q0, q1, q2, q3; };

// Robust scalar-frequency decode (2400000000 in any plausible encoding).
__device__ __forceinline__ float read_freq(const void* p) {
    const unsigned* w = (const unsigned*)p;
    unsigned lo = w[0];
    float ff = __uint_as_float(lo);
    if (ff >= 1.0e5f && ff <= 1.0e13f) return ff;       // float32
    if (lo != 0u) return (float)lo;                      // int32-wrap / int64 lo
    double d = *(const double*)p;                        // lo==0 -> 8-byte dtype
    if (d >= 1.0e5 && d <= 1.0e13) return (float)d;      // float64
    unsigned long long v = ((unsigned long long)w[1] << 32) | lo;
    return (float)v;                                     // int64 (hi-word path)
}

__global__ __launch_bounds__(BLK) void prep_kernel(
        const float* __restrict__ pos,
        const float* __restrict__ scl,
        const float* __restrict__ amp,
        const float* __restrict__ ph,
        PrimDup* __restrict__ pd) {
    int p = blockIdx.x * blockDim.x + threadIdx.x;
    if (p >= NPRIMS) return;
    const float KE     = -0.72134752044448169f;   // -0.5*log2(e)
    const float INV2PI =  0.15915494309189535f;
    float sx = scl[3*p+0], sy = scl[3*p+1], sz = scl[3*p+2];
    float gx = KE / (sx*sx), gy = KE / (sy*sy), gz = KE / (sz*sz);
    float pr = ph[p] * INV2PI;
    PrimDup D;
    D.q0 = make_float4(pos[3*p+0], pos[3*p+0], pos[3*p+1], pos[3*p+1]);
    D.q1 = make_float4(pos[3*p+2], pos[3*p+2], amp[p], amp[p]);
    D.q2 = make_float4(gx, gx, gy, gy);
    D.q3 = make_float4(gz, gz, pr, pr);
    pd[p] = D;
}

// Each block: BLK*2 points (2 per thread, packed in v2f) x (NPRIMS/NSPLIT)
// prims. Prim scalars arrive as duplicated SGPR pairs (wave-uniform s_load)
// feeding pk ops as broadcast operands; points live in VGPRs.
template <int NSPLIT>
__global__ __launch_bounds__(BLK) void field_kernel(
        const float* __restrict__ qp,
        const PrimDup* __restrict__ pd,
        const void* __restrict__ freq_p,
        float2* __restrict__ part) {
    constexpr int PCOUNT = NPRIMS / NSPLIT;        // prims per block
    const int n0 = blockIdx.x * (BLK * 2) + threadIdx.x;
    const int n1 = n0 + BLK;
    const float kr = read_freq(freq_p) / 299792458.0f;   // cycles per metre
    const v2f kr2 = {kr, kr};

    // 2 points packed per v2f: lane-local VGPR data, loaded once.
    const v2f xx = {qp[3*n0+0], qp[3*n1+0]};
    const v2f yy = {qp[3*n0+1], qp[3*n1+1]};
    const v2f zz = {qp[3*n0+2], qp[3*n1+2]};

    v2f re = {0.0f, 0.0f}, im = {0.0f, 0.0f};

    const int base = blockIdx.y * PCOUNT;
    #pragma unroll 4
    for (int j = 0; j < PCOUNT; ++j) {
        PrimDup D = pd[base + j];                  // wave-uniform -> s_load x16
        // Duplicated halves: {D.q0.x, D.q0.y} is an even-aligned SGPR pair
        // holding (mux, mux) -> direct VOP3P broadcast operand.
        v2f mux = {D.q0.x, D.q0.y}, muy = {D.q0.z, D.q0.w};
        v2f muz = {D.q1.x, D.q1.y}, am2 = {D.q1.z, D.q1.w};
        v2f gx  = {D.q2.x, D.q2.y}, gy  = {D.q2.z, D.q2.w};
        v2f gz  = {D.q3.x, D.q3.y}, ph2 = {D.q3.z, D.q3.w};

        v2f dx = xx - mux, dy = yy - muy, dz = zz - muz;
        v2f t0 = dx * dx, t1 = dy * dy, t2 = dz * dz;
        v2f e  = t0 * gx + t1 * gy + t2 * gz;      // <= 0 (pk_fma chain)
        v2f d2 = t0 + t1 + t2;
        d2 = __builtin_elementwise_max(d2, (v2f){1e-12f, 1e-12f});

        v2f r2 = {__builtin_amdgcn_sqrtf(d2.x), __builtin_amdgcn_sqrtf(d2.y)};
        v2f ex = {__builtin_amdgcn_exp2f(e.x),  __builtin_amdgcn_exp2f(e.y)};
        v2f w2 = am2 * ex;
        v2f tp = __builtin_elementwise_fma(kr2, r2, ph2);   // revolutions
        float f0 = __builtin_amdgcn_fractf(tp.x);
        float f1 = __builtin_amdgcn_fractf(tp.y);
        v2f s2 = {__builtin_amdgcn_sinf(f0), __builtin_amdgcn_sinf(f1)};
        v2f c2 = {__builtin_amdgcn_cosf(f0), __builtin_amdgcn_cosf(f1)};
        re = __builtin_elementwise_fma(w2, c2, re);
        im = __builtin_elementwise_fma(w2, s2, im);
    }

    part[(size_t)blockIdx.y * NPOINTS + n0] = make_float2(re.x, im.x);
    part[(size_t)blockIdx.y * NPOINTS + n1] = make_float2(re.y, im.y);
}

template <int NSPLIT>
__global__ __launch_bounds__(BLK) void reduce_kernel(const float2* __restrict__ part,
                                                     float* __restrict__ out) {
    int n = blockIdx.x * blockDim.x + threadIdx.x;
    float re = 0.0f, im = 0.0f;
    #pragma unroll
    for (int s = 0; s < NSPLIT; ++s) {
        float2 v = part[(size_t)s * NPOINTS + n];
        re += v.x; im += v.y;
    }
    out[n]           = re;   // planar: real block then imag block
    out[NPOINTS + n] = im;
}

// Fallback (tiny workspace): LDS kernel, single pass, direct planar output.
__global__ __launch_bounds__(BLK) void field_fallback(
        const float* __restrict__ qp,
        const float* __restrict__ pos,
        const float* __restrict__ scl,
        const float* __restrict__ amp,
        const float* __restrict__ ph,
        const void*  __restrict__ freq_p,
        float*       __restrict__ out) {
    __shared__ float4 sA[128];
    __shared__ float4 sB[128];
    const int n = blockIdx.x * BLK + threadIdx.x;
    const float x = qp[3*n+0], y = qp[3*n+1], z = qp[3*n+2];
    const float kr = read_freq(freq_p) / 299792458.0f;
    const float KE = -0.72134752044448169f, INV2PI = 0.15915494309189535f;
    float re = 0.0f, im = 0.0f;
    for (int tile = 0; tile < NPRIMS / 128; ++tile) {
        __syncthreads();
        if (threadIdx.x < 128) {
            int p = tile * 128 + threadIdx.x;
            float sx = scl[3*p+0], sy = scl[3*p+1], sz = scl[3*p+2];
            sA[threadIdx.x] = make_float4(pos[3*p+0], pos[3*p+1], pos[3*p+2], amp[p]);
            sB[threadIdx.x] = make_float4(KE/(sx*sx), KE/(sy*sy), KE/(sz*sz), ph[p]*INV2PI);
        }
        __syncthreads();
        #pragma unroll 8
        for (int p = 0; p < 128; ++p) {
            float4 a = sA[p];
            float4 b = sB[p];
            float dx = x - a.x, dy = y - a.y, dz = z - a.z;
            float t0 = dx*dx, t1 = dy*dy, t2 = dz*dz;
            float e  = fmaf(t0, b.x, fmaf(t1, b.y, t2 * b.z));
            float d2 = t0 + t1 + t2;
            float r  = __builtin_amdgcn_sqrtf(fmaxf(d2, 1e-12f));
            float w  = a.w * __builtin_amdgcn_exp2f(e);
            float tp = __builtin_amdgcn_fractf(fmaf(kr, r, b.w));
            float s  = __builtin_amdgcn_sinf(tp);
            float c  = __builtin_amdgcn_cosf(tp);
            re = fmaf(w, c, re);
            im = fmaf(w, s, im);
        }
    }
    out[n]           = re;
    out[NPOINTS + n] = im;
}

extern "C" void kernel_launch(void* const* d_in, const int* in_sizes, int n_in,
                              void* d_out, int out_size, void* d_ws, size_t ws_size,
                              hipStream_t stream) {
    const float* qp  = (const float*)d_in[0];
    const float* pos = (const float*)d_in[1];
    const float* scl = (const float*)d_in[2];
    const float* amp = (const float*)d_in[3];
    const float* ph  = (const float*)d_in[4];
    const void*  fq  = d_in[5];
    float* out = (float*)d_out;

    const size_t packed_bytes = (size_t)NPRIMS * sizeof(PrimDup);            // 128 KB
    const size_t ps32 = packed_bytes + (size_t)32 * NPOINTS * sizeof(float2); // +8 MB
    const size_t ps16 = packed_bytes + (size_t)16 * NPOINTS * sizeof(float2); // +4 MB

    if (ws_size >= ps32) {
        // 2048 blocks, 2 points/thread (v2f-packed), 64 prims per block
        PrimDup* pd   = (PrimDup*)d_ws;
        float2*  part = (float2*)((char*)d_ws + packed_bytes);
        prep_kernel<<<dim3(NPRIMS / BLK), dim3(BLK), 0, stream>>>(pos, scl, amp, ph, pd);
        field_kernel<32><<<dim3(NPOINTS / (BLK * 2), 32), dim3(BLK), 0, stream>>>(qp, pd, fq, part);
        reduce_kernel<32><<<dim3(NPOINTS / BLK), dim3(BLK), 0, stream>>>(part, out);
    } else if (ws_size >= ps16) {
        PrimDup* pd   = (PrimDup*)d_ws;
        float2*  part = (float2*)((char*)d_ws + packed_bytes);
        prep_kernel<<<dim3(NPRIMS / BLK), dim3(BLK), 0, stream>>>(pos, scl, amp, ph, pd);
        field_kernel<16><<<dim3(NPOINTS / (BLK * 2), 16), dim3(BLK), 0, stream>>>(qp, pd, fq, part);
        reduce_kernel<16><<<dim3(NPOINTS / BLK), dim3(BLK), 0, stream>>>(part, out);
    } else {
        field_fallback<<<dim3(NPOINTS / BLK), dim3(BLK), 0, stream>>>(qp, pos, scl, amp, ph, fq, out);
    }
}